// Round 1
// baseline (338.614 us; speedup 1.0000x reference)
//
#include <hip/hip_runtime.h>
#include <math.h>

// Problem constants (fixed by the reference): N=50000, E=800000, IN_DIM=128,
// HEADS=8, F_OUT=16, HF=128.

// ---------------------------------------------------------------------------
// K1: proj = x @ W_proj^T, skip = x @ W_skip^T.
// 1 wave/block, 16 nodes/block staged in LDS, 4 output cols per thread
// (proj c, proj c+64, skip c, skip c+64) so VALU ~= LDS pipe.
// ---------------------------------------------------------------------------
__global__ __launch_bounds__(64) void k_proj(const float* __restrict__ x,
                                             const float* __restrict__ Wp,
                                             const float* __restrict__ Ws,
                                             float* __restrict__ proj,
                                             float* __restrict__ skip) {
  __shared__ float xs[16 * 128];
  const int t = threadIdx.x;  // 0..63
  const size_t base = (size_t)blockIdx.x * 16;

  // stage 16 x-rows (8 KB), coalesced float4
  const float4* xg = (const float4*)(x + base * 128);
  float4* xl = (float4*)xs;
#pragma unroll
  for (int i = 0; i < 8; ++i) xl[t + i * 64] = xg[t + i * 64];
  __syncthreads();

  const float4* w0 = (const float4*)(Wp + (size_t)t * 128);
  const float4* w1 = (const float4*)(Wp + (size_t)(t + 64) * 128);
  const float4* w2 = (const float4*)(Ws + (size_t)t * 128);
  const float4* w3 = (const float4*)(Ws + (size_t)(t + 64) * 128);

  float acc0[16], acc1[16], acc2[16], acc3[16];
#pragma unroll
  for (int n = 0; n < 16; ++n) { acc0[n] = 0.f; acc1[n] = 0.f; acc2[n] = 0.f; acc3[n] = 0.f; }

  for (int k4 = 0; k4 < 32; ++k4) {
    float4 a0 = w0[k4];
    float4 a1 = w1[k4];
    float4 a2 = w2[k4];
    float4 a3 = w3[k4];
#pragma unroll
    for (int n = 0; n < 16; ++n) {
      float4 xv = *(const float4*)(xs + n * 128 + k4 * 4);  // wave-uniform addr -> LDS broadcast
      acc0[n] = fmaf(a0.x, xv.x, fmaf(a0.y, xv.y, fmaf(a0.z, xv.z, fmaf(a0.w, xv.w, acc0[n]))));
      acc1[n] = fmaf(a1.x, xv.x, fmaf(a1.y, xv.y, fmaf(a1.z, xv.z, fmaf(a1.w, xv.w, acc1[n]))));
      acc2[n] = fmaf(a2.x, xv.x, fmaf(a2.y, xv.y, fmaf(a2.z, xv.z, fmaf(a2.w, xv.w, acc2[n]))));
      acc3[n] = fmaf(a3.x, xv.x, fmaf(a3.y, xv.y, fmaf(a3.z, xv.z, fmaf(a3.w, xv.w, acc3[n]))));
    }
  }

#pragma unroll
  for (int n = 0; n < 16; ++n) {
    size_t row = (base + n) * 128;
    proj[row + t] = acc0[n];
    proj[row + t + 64] = acc1[n];
    skip[row + t] = acc2[n];
    skip[row + t + 64] = acc3[n];
  }
}

// ---------------------------------------------------------------------------
// K1b: per-node per-head partial scores s_src, s_tgt (dot of proj head slice
// with a_src[h], a_tgt[h]).
// ---------------------------------------------------------------------------
__global__ void k_scores(const float* __restrict__ proj,
                         const float* __restrict__ a_src,
                         const float* __restrict__ a_tgt,
                         float* __restrict__ ssrc, float* __restrict__ stgt, int N) {
  int idx = blockIdx.x * blockDim.x + threadIdx.x;
  if (idx >= N * 8) return;
  int n = idx >> 3;
  int h = idx & 7;
  const float* p = proj + (size_t)n * 128 + h * 16;
  const float* as = a_src + h * 16;
  const float* at = a_tgt + h * 16;
  float s1 = 0.f, s2 = 0.f;
#pragma unroll
  for (int f = 0; f < 16; ++f) {
    float pv = p[f];
    s1 = fmaf(pv, as[f], s1);
    s2 = fmaf(pv, at[f], s2);
  }
  ssrc[idx] = s1;
  stgt[idx] = s2;
}

// ---------------------------------------------------------------------------
// CSR build: histogram of tgt, exclusive scan, scatter src ids by tgt.
// ---------------------------------------------------------------------------
__global__ void k_count(const int* __restrict__ tgt, int* __restrict__ counts, int E) {
  int e = blockIdx.x * blockDim.x + threadIdx.x;
  if (e < E) atomicAdd(&counts[tgt[e]], 1);
}

__global__ __launch_bounds__(1024) void k_scan1(const int* __restrict__ counts,
                                                int* __restrict__ offs,
                                                int* __restrict__ bsums, int N) {
  __shared__ int sm[1024];
  int t = threadIdx.x;
  int i = blockIdx.x * 1024 + t;
  int v = (i < N) ? counts[i] : 0;
  sm[t] = v;
  __syncthreads();
  for (int off = 1; off < 1024; off <<= 1) {
    int u = (t >= off) ? sm[t - off] : 0;
    __syncthreads();
    sm[t] += u;
    __syncthreads();
  }
  if (i < N) offs[i] = sm[t] - v;          // block-local exclusive
  if (t == 1023) bsums[blockIdx.x] = sm[t];  // block total
}

__global__ void k_scan2(int* __restrict__ bsums, int nb) {
  int l = threadIdx.x;  // 64 threads, nb <= 64
  int v = (l < nb) ? bsums[l] : 0;
  int orig = v;
#pragma unroll
  for (int off = 1; off < 64; off <<= 1) {
    int u = __shfl_up(v, off);
    if (l >= off) v += u;
  }
  if (l < nb) bsums[l] = v - orig;  // exclusive
}

__global__ void k_scan3(int* __restrict__ offs, const int* __restrict__ bsums,
                        int* __restrict__ nxt, int N, int E) {
  int i = blockIdx.x * blockDim.x + threadIdx.x;
  if (i < N) {
    int o = offs[i] + bsums[i >> 10];
    offs[i] = o;
    nxt[i] = o;
  }
  if (i == 0) offs[N] = E;
}

__global__ void k_scatter(const int* __restrict__ ei, int* __restrict__ nxt,
                          int* __restrict__ esrc, int E) {
  int e = blockIdx.x * blockDim.x + threadIdx.x;
  if (e < E) {
    int t = ei[E + e];  // tgt
    int p = atomicAdd(&nxt[t], 1);
    esrc[p] = ei[e];  // src
  }
}

// ---------------------------------------------------------------------------
// K3: one wave per target node. Online softmax (no max shift -- scores are
// O(1), exp cannot overflow; softmax is shift-invariant so result matches).
// Lane l handles feature cols 2l,2l+1 (head h = l>>3). All lanes of a head
// group compute the identical denom redundantly -> no cross-lane reduce.
// Fused: skip + bias + ELU, writes d_out directly.
// ---------------------------------------------------------------------------
__global__ __launch_bounds__(256) void k_agg(const float* __restrict__ proj,
                                             const float* __restrict__ skip,
                                             const float* __restrict__ ssrc,
                                             const float* __restrict__ stgt,
                                             const float* __restrict__ bias,
                                             const int* __restrict__ offs,
                                             const int* __restrict__ esrc,
                                             float* __restrict__ out, int N) {
  int wave = (int)((blockIdx.x * (size_t)blockDim.x + threadIdx.x) >> 6);
  int lane = threadIdx.x & 63;
  if (wave >= N) return;  // whole wave exits together
  const int n = wave;
  const int c = lane * 2;
  const int h = c >> 4;

  const float st = stgt[n * 8 + h];
  const int begin = offs[n];
  const int end = offs[n + 1];

  float acc0 = 0.f, acc1 = 0.f, dsum = 0.f;

  for (int base = begin; base < end; base += 64) {
    int cnt = min(64, end - base);
    int srcv = (lane < cnt) ? esrc[base + lane] : 0;
    for (int j = 0; j < cnt; ++j) {
      int s = __shfl(srcv, j);
      float e = ssrc[s * 8 + h] + st;
      e = (e > 0.f) ? e : 0.2f * e;      // LeakyReLU(0.2)
      float w = __expf(e);
      dsum += w;
      float2 p = *(const float2*)(proj + (size_t)s * 128 + c);
      acc0 = fmaf(w, p.x, acc0);
      acc1 = fmaf(w, p.y, acc1);
    }
  }

  const float inv = 1.0f / (dsum + 1e-16f);
  size_t row = (size_t)n * 128;
  float r0 = acc0 * inv + skip[row + c] + bias[c];
  float r1 = acc1 * inv + skip[row + c + 1] + bias[c + 1];
  r0 = (r0 > 0.f) ? r0 : (expf(r0) - 1.0f);  // ELU
  r1 = (r1 > 0.f) ? r1 : (expf(r1) - 1.0f);
  float2 res = make_float2(r0, r1);
  *(float2*)(out + row + c) = res;
}

// ---------------------------------------------------------------------------
extern "C" void kernel_launch(void* const* d_in, const int* in_sizes, int n_in,
                              void* d_out, int out_size, void* d_ws, size_t ws_size,
                              hipStream_t stream) {
  const float* x = (const float*)d_in[0];
  const int* ei = (const int*)d_in[1];
  const float* Wp = (const float*)d_in[2];
  const float* a_src = (const float*)d_in[3];
  const float* a_tgt = (const float*)d_in[4];
  const float* Ws = (const float*)d_in[5];
  const float* bias = (const float*)d_in[6];
  float* out = (float*)d_out;

  const int N = in_sizes[0] / 128;  // 50000
  const int E = in_sizes[1] / 2;    // 800000

  // workspace layout (floats/ints, all 4B): ~58.3 MB total
  float* proj = (float*)d_ws;                   // N*128
  float* skip = proj + (size_t)N * 128;         // N*128
  float* ssrc = skip + (size_t)N * 128;         // N*8
  float* stgt = ssrc + (size_t)N * 8;           // N*8
  int* counts = (int*)(stgt + (size_t)N * 8);   // N
  int* offs = counts + N;                       // N+1
  int* nxt = offs + N + 1;                      // N
  int* bsums = nxt + N;                         // 64
  int* esrc = bsums + 64;                       // E

  const int nb = (N + 1023) / 1024;

  hipMemsetAsync(counts, 0, (size_t)N * sizeof(int), stream);

  k_proj<<<N / 16, 64, 0, stream>>>(x, Wp, Ws, proj, skip);
  k_scores<<<(N * 8 + 255) / 256, 256, 0, stream>>>(proj, a_src, a_tgt, ssrc, stgt, N);
  k_count<<<(E + 255) / 256, 256, 0, stream>>>(ei + E, counts, E);
  k_scan1<<<nb, 1024, 0, stream>>>(counts, offs, bsums, N);
  k_scan2<<<1, 64, 0, stream>>>(bsums, nb);
  k_scan3<<<(N + 255) / 256, 256, 0, stream>>>(offs, bsums, nxt, N, E);
  k_scatter<<<(E + 255) / 256, 256, 0, stream>>>(ei, nxt, esrc, E);
  k_agg<<<(N + 3) / 4, 256, 0, stream>>>(proj, skip, ssrc, stgt, bias, offs, esrc, out, N);
}

// Round 2
// 269.751 us; speedup vs baseline: 1.2553x; 1.2553x over previous
//
#include <hip/hip_runtime.h>
#include <hip/hip_bf16.h>
#include <math.h>

// N=50000, E=800000, IN_DIM=128, HEADS=8, F_OUT=16, HF=128.
// Pad rows to multiple of 64 for the MFMA GEMM.
#define PADN 50048

typedef __attribute__((ext_vector_type(8))) short short8;
typedef __attribute__((ext_vector_type(4))) float f32x4;

__device__ __forceinline__ unsigned short f2b(float f) {
  __hip_bfloat16 h = __float2bfloat16(f);
  return *(unsigned short*)&h;
}

// ---------------------------------------------------------------------------
// K0: x fp32 -> xb bf16, zero-padded to PADN rows.
// ---------------------------------------------------------------------------
__global__ void k_cvt(const float* __restrict__ x, unsigned short* __restrict__ xb, int nelem) {
  int idx = blockIdx.x * blockDim.x + threadIdx.x;  // one float4 per thread
  if (idx * 4 >= PADN * 128) return;
  float4 v = make_float4(0.f, 0.f, 0.f, 0.f);
  if (idx * 4 < nelem) v = ((const float4*)x)[idx];
  ushort4 o;
  o.x = f2b(v.x); o.y = f2b(v.y); o.z = f2b(v.z); o.w = f2b(v.w);
  ((ushort4*)xb)[idx] = o;
}

// ---------------------------------------------------------------------------
// K0b: pack [W_proj; W_skip] into MFMA B-fragment order.
// Bpk[((tile*4+ks)*64+lane)*8 + j] = Wt[k][col], col=tile*16+(lane&15),
// k = ks*32 + (lane>>4)*8 + j.  Wt[k][col] = W[col][k] (W row-major [128,128]).
// ---------------------------------------------------------------------------
__global__ void k_wpack(const float* __restrict__ Wp, const float* __restrict__ Ws,
                        unsigned short* __restrict__ Bpk) {
  int idx = blockIdx.x * blockDim.x + threadIdx.x;  // 0..4095 lane-entries
  if (idx >= 16 * 4 * 64) return;
  int tile = idx >> 8;
  int ks = (idx >> 6) & 3;
  int lane = idx & 63;
  int col = tile * 16 + (lane & 15);
  int kbase = ks * 32 + (lane >> 4) * 8;
  const float* src = (col < 128) ? (Wp + (size_t)col * 128 + kbase)
                                 : (Ws + (size_t)(col - 128) * 128 + kbase);
  unsigned short o[8];
#pragma unroll
  for (int j = 0; j < 8; ++j) o[j] = f2b(src[j]);
  *(short8*)(Bpk + (size_t)idx * 8) = *(short8*)o;
}

// ---------------------------------------------------------------------------
// K1: MFMA GEMM: [PADN,128] @ [128,256] -> proj bf16 (cols 0-127), skip bf16
// (cols 128-255). Block = 4 waves; wave w handles rows r0=block*64+w*16,
// loops all 16 col-tiles. A-frags held in registers across the tile loop.
// ---------------------------------------------------------------------------
__global__ __launch_bounds__(256) void k_gemm(const unsigned short* __restrict__ xb,
                                              const unsigned short* __restrict__ Bpk,
                                              unsigned short* __restrict__ pb,
                                              unsigned short* __restrict__ sb, int N) {
  const int wave = threadIdx.x >> 6;
  const int lane = threadIdx.x & 63;
  const int m = lane & 15;
  const int q = lane >> 4;
  const int r0 = blockIdx.x * 64 + wave * 16;

  short8 a[4];
#pragma unroll
  for (int ks = 0; ks < 4; ++ks)
    a[ks] = *(const short8*)(xb + (size_t)(r0 + m) * 128 + ks * 32 + q * 8);

  for (int ct = 0; ct < 16; ++ct) {
    f32x4 acc = {0.f, 0.f, 0.f, 0.f};
#pragma unroll
    for (int ks = 0; ks < 4; ++ks) {
      short8 b = *(const short8*)(Bpk + (size_t)((ct * 4 + ks) * 64 + lane) * 8);
      acc = __builtin_amdgcn_mfma_f32_16x16x32_bf16(a[ks], b, acc, 0, 0, 0);
    }
#pragma unroll
    for (int r = 0; r < 4; ++r) {
      int row = r0 + q * 4 + r;
      if (row < N) {
        if (ct < 8)
          pb[(size_t)row * 128 + ct * 16 + m] = f2b(acc[r]);
        else
          sb[(size_t)row * 128 + (ct - 8) * 16 + m] = f2b(acc[r]);
      }
    }
  }
}

// ---------------------------------------------------------------------------
// K1b: per-node per-head scores from bf16 proj.
// ---------------------------------------------------------------------------
__global__ void k_scores(const unsigned short* __restrict__ pb,
                         const float* __restrict__ a_src,
                         const float* __restrict__ a_tgt,
                         float* __restrict__ ssrc, float* __restrict__ stgt, int N) {
  int idx = blockIdx.x * blockDim.x + threadIdx.x;
  if (idx >= N * 8) return;
  int n = idx >> 3;
  int h = idx & 7;
  const unsigned int* p = (const unsigned int*)(pb + (size_t)n * 128 + h * 16);
  const float* as = a_src + h * 16;
  const float* at = a_tgt + h * 16;
  float s1 = 0.f, s2 = 0.f;
#pragma unroll
  for (int f = 0; f < 8; ++f) {
    unsigned int u = p[f];
    float p0 = __uint_as_float(u << 16);
    float p1 = __uint_as_float(u & 0xffff0000u);
    s1 = fmaf(p0, as[2 * f], fmaf(p1, as[2 * f + 1], s1));
    s2 = fmaf(p0, at[2 * f], fmaf(p1, at[2 * f + 1], s2));
  }
  ssrc[idx] = s1;
  stgt[idx] = s2;
}

// ---------------------------------------------------------------------------
// CSR build: histogram of tgt, exclusive scan, scatter src ids by tgt.
// ---------------------------------------------------------------------------
__global__ void k_count(const int* __restrict__ tgt, int* __restrict__ counts, int E) {
  int e = blockIdx.x * blockDim.x + threadIdx.x;
  if (e < E) atomicAdd(&counts[tgt[e]], 1);
}

__global__ __launch_bounds__(1024) void k_scan1(const int* __restrict__ counts,
                                                int* __restrict__ offs,
                                                int* __restrict__ bsums, int N) {
  __shared__ int sm[1024];
  int t = threadIdx.x;
  int i = blockIdx.x * 1024 + t;
  int v = (i < N) ? counts[i] : 0;
  sm[t] = v;
  __syncthreads();
  for (int off = 1; off < 1024; off <<= 1) {
    int u = (t >= off) ? sm[t - off] : 0;
    __syncthreads();
    sm[t] += u;
    __syncthreads();
  }
  if (i < N) offs[i] = sm[t] - v;
  if (t == 1023) bsums[blockIdx.x] = sm[t];
}

__global__ void k_scan2(int* __restrict__ bsums, int nb) {
  int l = threadIdx.x;
  int v = (l < nb) ? bsums[l] : 0;
  int orig = v;
#pragma unroll
  for (int off = 1; off < 64; off <<= 1) {
    int u = __shfl_up(v, off);
    if (l >= off) v += u;
  }
  if (l < nb) bsums[l] = v - orig;
}

__global__ void k_scan3(int* __restrict__ offs, const int* __restrict__ bsums,
                        int* __restrict__ nxt, int N, int E) {
  int i = blockIdx.x * blockDim.x + threadIdx.x;
  if (i < N) {
    int o = offs[i] + bsums[i >> 10];
    offs[i] = o;
    nxt[i] = o;
  }
  if (i == 0) offs[N] = E;
}

__global__ void k_scatter(const int* __restrict__ ei, int* __restrict__ nxt,
                          int* __restrict__ esrc, int E) {
  int e = blockIdx.x * blockDim.x + threadIdx.x;
  if (e < E) {
    int t = ei[E + e];
    int p = atomicAdd(&nxt[t], 1);
    esrc[p] = ei[e];
  }
}

// ---------------------------------------------------------------------------
// K3: one wave per target node; online softmax (shift-free; scores O(1)),
// bf16 proj gathers with depth-1 prefetch; fused skip+bias+ELU.
// Lane l: feature cols 2l,2l+1; head h=l>>3.
// ---------------------------------------------------------------------------
__global__ __launch_bounds__(256) void k_agg(const unsigned short* __restrict__ pb,
                                             const unsigned short* __restrict__ sb,
                                             const float* __restrict__ ssrc,
                                             const float* __restrict__ stgt,
                                             const float* __restrict__ bias,
                                             const int* __restrict__ offs,
                                             const int* __restrict__ esrc,
                                             float* __restrict__ out, int N) {
  int wave = (int)((blockIdx.x * (size_t)blockDim.x + threadIdx.x) >> 6);
  int lane = threadIdx.x & 63;
  if (wave >= N) return;
  const int n = wave;
  const int c = lane * 2;
  const int h = lane >> 3;

  const float st = stgt[n * 8 + h];
  const int begin = offs[n];
  const int end = offs[n + 1];

  float acc0 = 0.f, acc1 = 0.f, dsum = 0.f;

  for (int base = begin; base < end; base += 64) {
    int cnt = min(64, end - base);
    int srcv = (lane < cnt) ? esrc[base + lane] : 0;
    int s = __shfl(srcv, 0);
    unsigned int pv = *(const unsigned int*)(pb + (size_t)s * 128 + c);
    float sc = ssrc[s * 8 + h];
    for (int j = 0; j < cnt; ++j) {
      int jn = (j + 1 < cnt) ? (j + 1) : (cnt - 1);
      int sn = __shfl(srcv, jn);
      unsigned int pnext = *(const unsigned int*)(pb + (size_t)sn * 128 + c);
      float scnext = ssrc[sn * 8 + h];
      float e = sc + st;
      e = (e > 0.f) ? e : 0.2f * e;        // LeakyReLU(0.2)
      float w = __expf(e);
      dsum += w;
      acc0 = fmaf(w, __uint_as_float(pv << 16), acc0);
      acc1 = fmaf(w, __uint_as_float(pv & 0xffff0000u), acc1);
      pv = pnext;
      sc = scnext;
    }
  }

  const float inv = 1.0f / (dsum + 1e-16f);
  size_t row = (size_t)n * 128;
  unsigned int su = *(const unsigned int*)(sb + row + c);
  float sk0 = __uint_as_float(su << 16);
  float sk1 = __uint_as_float(su & 0xffff0000u);
  float r0 = fmaf(acc0, inv, sk0) + bias[c];
  float r1 = fmaf(acc1, inv, sk1) + bias[c + 1];
  r0 = (r0 > 0.f) ? r0 : (expf(r0) - 1.0f);  // ELU
  r1 = (r1 > 0.f) ? r1 : (expf(r1) - 1.0f);
  *(float2*)(out + row + c) = make_float2(r0, r1);
}

// ---------------------------------------------------------------------------
extern "C" void kernel_launch(void* const* d_in, const int* in_sizes, int n_in,
                              void* d_out, int out_size, void* d_ws, size_t ws_size,
                              hipStream_t stream) {
  const float* x = (const float*)d_in[0];
  const int* ei = (const int*)d_in[1];
  const float* Wp = (const float*)d_in[2];
  const float* a_src = (const float*)d_in[3];
  const float* a_tgt = (const float*)d_in[4];
  const float* Ws = (const float*)d_in[5];
  const float* bias = (const float*)d_in[6];
  float* out = (float*)d_out;

  const int N = in_sizes[0] / 128;  // 50000
  const int E = in_sizes[1] / 2;    // 800000

  // workspace layout (~45.5 MB)
  unsigned short* xb = (unsigned short*)d_ws;       // PADN*128 bf16
  unsigned short* Bpk = xb + (size_t)PADN * 128;    // 32768 bf16
  unsigned short* pb = Bpk + 32768;                 // N*128 bf16
  unsigned short* sb = pb + (size_t)N * 128;        // N*128 bf16
  float* ssrc = (float*)(sb + (size_t)N * 128);     // N*8
  float* stgt = ssrc + (size_t)N * 8;               // N*8
  int* counts = (int*)(stgt + (size_t)N * 8);       // N
  int* offs = counts + N;                           // N+1
  int* nxt = offs + N + 1;                          // N
  int* bsums = nxt + N;                             // 64
  int* esrc = bsums + 64;                           // E

  const int nb = (N + 1023) / 1024;

  hipMemsetAsync(counts, 0, (size_t)N * sizeof(int), stream);

  k_cvt<<<(PADN * 128 / 4 + 255) / 256, 256, 0, stream>>>(x, xb, N * 128);
  k_wpack<<<16, 256, 0, stream>>>(Wp, Ws, Bpk);
  k_gemm<<<PADN / 64, 256, 0, stream>>>(xb, Bpk, pb, sb, N);
  k_scores<<<(N * 8 + 255) / 256, 256, 0, stream>>>(pb, a_src, a_tgt, ssrc, stgt, N);
  k_count<<<(E + 255) / 256, 256, 0, stream>>>(ei + E, counts, E);
  k_scan1<<<nb, 1024, 0, stream>>>(counts, offs, bsums, N);
  k_scan2<<<1, 64, 0, stream>>>(bsums, nb);
  k_scan3<<<(N + 255) / 256, 256, 0, stream>>>(offs, bsums, nxt, N, E);
  k_scatter<<<(E + 255) / 256, 256, 0, stream>>>(ei, nxt, esrc, E);
  k_agg<<<(N + 3) / 4, 256, 0, stream>>>(pb, sb, ssrc, stgt, bias, offs, esrc, out, N);
}

// Round 3
// 258.673 us; speedup vs baseline: 1.3090x; 1.0428x over previous
//
#include <hip/hip_runtime.h>
#include <hip/hip_bf16.h>
#include <math.h>

// N=50000, E=800000, IN_DIM=128, HEADS=8, F_OUT=16, HF=128.
#define PADN 50048
#define CVB (PADN / 8)  // blocks for the cvt part of k_prep (PADN*128/4 float4s / 256 thr)

typedef __attribute__((ext_vector_type(8))) short short8;
typedef __attribute__((ext_vector_type(4))) float f32x4;

__device__ __forceinline__ unsigned short f2b(float f) {
  __hip_bfloat16 h = __float2bfloat16(f);
  return *(unsigned short*)&h;
}

// ---------------------------------------------------------------------------
// K_prep: fused (a) x fp32->bf16 padded, (b) W-pack into MFMA B-frag order,
// (c) zero counts.  Branch is block-uniform.
// ---------------------------------------------------------------------------
__global__ __launch_bounds__(256) void k_prep(const float* __restrict__ x,
                                              const float* __restrict__ Wp,
                                              const float* __restrict__ Ws,
                                              unsigned short* __restrict__ xb,
                                              unsigned short* __restrict__ Bpk,
                                              int* __restrict__ counts,
                                              int nelem, int N) {
  const int b = blockIdx.x;
  if (b < CVB) {
    int idx = b * 256 + threadIdx.x;  // one float4 per thread
    float4 v = make_float4(0.f, 0.f, 0.f, 0.f);
    if (idx * 4 < nelem) v = ((const float4*)x)[idx];
    ushort4 o;
    o.x = f2b(v.x); o.y = f2b(v.y); o.z = f2b(v.z); o.w = f2b(v.w);
    ((ushort4*)xb)[idx] = o;
  } else if (b < CVB + 16) {
    // Bpk[((tile*4+ks)*64+lane)*8 + j] = W[col][k], col=tile*16+(lane&15),
    // k = ks*32 + (lane>>4)*8 + j; cols 128..255 come from W_skip.
    int idx = (b - CVB) * 256 + threadIdx.x;  // 0..4095
    int tile = idx >> 8;
    int ks = (idx >> 6) & 3;
    int lane = idx & 63;
    int col = tile * 16 + (lane & 15);
    int kbase = ks * 32 + (lane >> 4) * 8;
    const float* src = (col < 128) ? (Wp + (size_t)col * 128 + kbase)
                                   : (Ws + (size_t)(col - 128) * 128 + kbase);
    unsigned short o[8];
#pragma unroll
    for (int j = 0; j < 8; ++j) o[j] = f2b(src[j]);
    *(short8*)(Bpk + (size_t)idx * 8) = *(short8*)o;
  } else {
    int i = (b - CVB - 16) * 256 + threadIdx.x;
    if (i < N) counts[i] = 0;
  }
}

// ---------------------------------------------------------------------------
// K_gemm: [PADN,128]bf16 @ [128,256] -> pb (cols 0-127), sb (cols 128-255),
// B staged in LDS once per block; per-node scores fused in the epilogue
// (cross-lane reduce of the fp32 accumulator over the 16-lane m-group).
// ---------------------------------------------------------------------------
__global__ __launch_bounds__(256) void k_gemm(const unsigned short* __restrict__ xb,
                                              const unsigned short* __restrict__ Bpk,
                                              unsigned short* __restrict__ pb,
                                              unsigned short* __restrict__ sb,
                                              float* __restrict__ ssrc,
                                              float* __restrict__ stgt,
                                              const float* __restrict__ a_src,
                                              const float* __restrict__ a_tgt, int N) {
  __shared__ unsigned short Bl[16 * 4 * 64 * 8];  // 64 KB
  {
    const uint4* bg = (const uint4*)Bpk;
    uint4* bl = (uint4*)Bl;
#pragma unroll
    for (int i = 0; i < 16; ++i) bl[threadIdx.x + i * 256] = bg[threadIdx.x + i * 256];
  }
  __syncthreads();

  const int wave = threadIdx.x >> 6, lane = threadIdx.x & 63;
  const int m = lane & 15, q = lane >> 4;
  const int r0 = blockIdx.x * 64 + wave * 16;

  short8 a[4];
#pragma unroll
  for (int ks = 0; ks < 4; ++ks)
    a[ks] = *(const short8*)(xb + (size_t)(r0 + m) * 128 + ks * 32 + q * 8);

  for (int ct = 0; ct < 16; ++ct) {
    f32x4 acc = {0.f, 0.f, 0.f, 0.f};
#pragma unroll
    for (int ks = 0; ks < 4; ++ks) {
      short8 bfr = *(const short8*)(Bl + (size_t)((ct * 4 + ks) * 64 + lane) * 8);
      acc = __builtin_amdgcn_mfma_f32_16x16x32_bf16(a[ks], bfr, acc, 0, 0, 0);
    }
    unsigned short* dst = (ct < 8) ? pb : sb;
    const int cc = (ct & 7) * 16 + m;
#pragma unroll
    for (int r = 0; r < 4; ++r) {
      int row = r0 + q * 4 + r;
      if (row < N) dst[(size_t)row * 128 + cc] = f2b(acc[r]);
    }
    if (ct < 8) {  // head ct: s_src/s_tgt dot over the 16 cols (lane dim m)
      const float as = a_src[ct * 16 + m];
      const float at = a_tgt[ct * 16 + m];
#pragma unroll
      for (int r = 0; r < 4; ++r) {
        float vs = acc[r] * as;
        float vt = acc[r] * at;
#pragma unroll
        for (int off = 8; off >= 1; off >>= 1) {
          vs += __shfl_xor(vs, off);
          vt += __shfl_xor(vt, off);
        }
        int row = r0 + q * 4 + r;
        if (m == 0 && row < N) {
          ssrc[row * 8 + ct] = vs;
          stgt[row * 8 + ct] = vt;
        }
      }
    }
  }
}

// ---------------------------------------------------------------------------
// CSR build
// ---------------------------------------------------------------------------
__global__ void k_count(const int* __restrict__ tgt, int* __restrict__ counts, int E) {
  int e = blockIdx.x * blockDim.x + threadIdx.x;
  if (e < E) atomicAdd(&counts[tgt[e]], 1);
}

__global__ __launch_bounds__(1024) void k_scan1(const int* __restrict__ counts,
                                                int* __restrict__ offs,
                                                int* __restrict__ bsums, int N) {
  __shared__ int sm[1024];
  int t = threadIdx.x;
  int i = blockIdx.x * 1024 + t;
  int v = (i < N) ? counts[i] : 0;
  sm[t] = v;
  __syncthreads();
  for (int off = 1; off < 1024; off <<= 1) {
    int u = (t >= off) ? sm[t - off] : 0;
    __syncthreads();
    sm[t] += u;
    __syncthreads();
  }
  if (i < N) offs[i] = sm[t] - v;          // block-local exclusive
  if (t == 1023) bsums[blockIdx.x] = sm[t];  // block total
}

// scan of block totals folded in: every wave scans bsums (nb<=64) in-register.
__global__ void k_scan3(int* __restrict__ offs, const int* __restrict__ bsums,
                        int* __restrict__ nxt, int N, int E, int nb) {
  int i = blockIdx.x * blockDim.x + threadIdx.x;
  int lane = threadIdx.x & 63;
  int incl = (lane < nb) ? bsums[lane] : 0;
#pragma unroll
  for (int off = 1; off < 64; off <<= 1) {
    int u = __shfl_up(incl, off);
    if (lane >= off) incl += u;
  }
  int g = i >> 10;  // wave-uniform (64 | 1024)
  int pre = __shfl(incl, (g > 0) ? (g - 1) : 0);
  if (g == 0) pre = 0;
  if (i < N) {
    int o = offs[i] + pre;
    offs[i] = o;
    nxt[i] = o;
  }
  if (i == 0) offs[N] = E;
}

__global__ void k_scatter(const int* __restrict__ ei, int* __restrict__ nxt,
                          int* __restrict__ esrc, int E) {
  int e = blockIdx.x * blockDim.x + threadIdx.x;
  if (e < E) {
    int t = ei[E + e];
    int p = atomicAdd(&nxt[t], 1);
    esrc[p] = ei[e];
  }
}

// ---------------------------------------------------------------------------
// K_agg: one wave per target node; shift-free online softmax; depth-8
// software-pipelined bf16 proj gathers (8 pv + 8 sc loads in flight, 4
// independent accumulator chains); fused skip+bias+ELU.
// Lane l: cols 2l,2l+1; head h=l>>3.
// ---------------------------------------------------------------------------
__global__ __launch_bounds__(256) void k_agg(const unsigned short* __restrict__ pb,
                                             const unsigned short* __restrict__ sb,
                                             const float* __restrict__ ssrc,
                                             const float* __restrict__ stgt,
                                             const float* __restrict__ bias,
                                             const int* __restrict__ offs,
                                             const int* __restrict__ esrc,
                                             float* __restrict__ out, int N) {
  int wid = (int)((blockIdx.x * (size_t)blockDim.x + threadIdx.x) >> 6);
  int lane = threadIdx.x & 63;
  if (wid >= N) return;
  const int n = wid;
  const int c = lane * 2;
  const int h = lane >> 3;

  const float st = stgt[n * 8 + h];
  const int begin = offs[n];
  const int end = offs[n + 1];

  float ds0 = 0.f, ds1 = 0.f, ds2 = 0.f, ds3 = 0.f;
  float x00 = 0.f, x01 = 0.f, x10 = 0.f, x11 = 0.f;
  float x20 = 0.f, x21 = 0.f, x30 = 0.f, x31 = 0.f;

  const unsigned short* pbc = pb + c;

#define FILLQ(p, jj)                                             \
  {                                                              \
    int s_ = __shfl(srcv, (jj));                                 \
    pv##p = *(const unsigned int*)(pbc + (size_t)s_ * 128);      \
    sc##p = ssrc[s_ * 8 + h];                                    \
  }
#define EDGEQ(p, dsx, a0x, a1x)                                  \
  {                                                              \
    float e_ = sc##p + st;                                       \
    e_ = (e_ > 0.f) ? e_ : 0.2f * e_;                            \
    float w_ = __expf(e_);                                       \
    dsx += w_;                                                   \
    a0x = fmaf(w_, __uint_as_float(pv##p << 16), a0x);           \
    a1x = fmaf(w_, __uint_as_float(pv##p & 0xffff0000u), a1x);   \
  }

  for (int base = begin; base < end; base += 64) {
    const int cnt = min(64, end - base);
    const int cm = cnt - 1;
    int srcv = esrc[base + min(lane, cm)];
    unsigned int pv0, pv1, pv2, pv3, pv4, pv5, pv6, pv7;
    float sc0, sc1, sc2, sc3, sc4, sc5, sc6, sc7;

    FILLQ(0, 0)
    FILLQ(1, min(1, cm))
    FILLQ(2, min(2, cm))
    FILLQ(3, min(3, cm))
    FILLQ(4, min(4, cm))
    FILLQ(5, min(5, cm))
    FILLQ(6, min(6, cm))
    FILLQ(7, min(7, cm))

    int j = 0;
    for (; j + 8 <= cnt; j += 8) {
      EDGEQ(0, ds0, x00, x01)
      EDGEQ(1, ds1, x10, x11)
      EDGEQ(2, ds2, x20, x21)
      EDGEQ(3, ds3, x30, x31)
      FILLQ(0, min(j + 8, cm))
      FILLQ(1, min(j + 9, cm))
      FILLQ(2, min(j + 10, cm))
      FILLQ(3, min(j + 11, cm))
      EDGEQ(4, ds0, x00, x01)
      EDGEQ(5, ds1, x10, x11)
      EDGEQ(6, ds2, x20, x21)
      EDGEQ(7, ds3, x30, x31)
      FILLQ(4, min(j + 12, cm))
      FILLQ(5, min(j + 13, cm))
      FILLQ(6, min(j + 14, cm))
      FILLQ(7, min(j + 15, cm))
    }
    const int rem = cnt - j;  // 0..7
    if (rem > 0) EDGEQ(0, ds0, x00, x01)
    if (rem > 1) EDGEQ(1, ds1, x10, x11)
    if (rem > 2) EDGEQ(2, ds2, x20, x21)
    if (rem > 3) EDGEQ(3, ds3, x30, x31)
    if (rem > 4) EDGEQ(4, ds0, x00, x01)
    if (rem > 5) EDGEQ(5, ds1, x10, x11)
    if (rem > 6) EDGEQ(6, ds2, x20, x21)
  }
#undef FILLQ
#undef EDGEQ

  const float dsum = (ds0 + ds1) + (ds2 + ds3);
  const float acc0 = (x00 + x10) + (x20 + x30);
  const float acc1 = (x01 + x11) + (x21 + x31);
  const float inv = 1.0f / (dsum + 1e-16f);
  size_t row = (size_t)n * 128;
  unsigned int su = *(const unsigned int*)(sb + row + c);
  float sk0 = __uint_as_float(su << 16);
  float sk1 = __uint_as_float(su & 0xffff0000u);
  float r0 = fmaf(acc0, inv, sk0) + bias[c];
  float r1 = fmaf(acc1, inv, sk1) + bias[c + 1];
  r0 = (r0 > 0.f) ? r0 : (expf(r0) - 1.0f);  // ELU
  r1 = (r1 > 0.f) ? r1 : (expf(r1) - 1.0f);
  *(float2*)(out + row + c) = make_float2(r0, r1);
}

// ---------------------------------------------------------------------------
extern "C" void kernel_launch(void* const* d_in, const int* in_sizes, int n_in,
                              void* d_out, int out_size, void* d_ws, size_t ws_size,
                              hipStream_t stream) {
  const float* x = (const float*)d_in[0];
  const int* ei = (const int*)d_in[1];
  const float* Wp = (const float*)d_in[2];
  const float* a_src = (const float*)d_in[3];
  const float* a_tgt = (const float*)d_in[4];
  const float* Ws = (const float*)d_in[5];
  const float* bias = (const float*)d_in[6];
  float* out = (float*)d_out;

  const int N = in_sizes[0] / 128;  // 50000
  const int E = in_sizes[1] / 2;    // 800000

  // workspace layout (~45.5 MB)
  unsigned short* xb = (unsigned short*)d_ws;       // PADN*128 bf16
  unsigned short* Bpk = xb + (size_t)PADN * 128;    // 32768 bf16
  unsigned short* pb = Bpk + 32768;                 // N*128 bf16
  unsigned short* sb = pb + (size_t)N * 128;        // N*128 bf16
  float* ssrc = (float*)(sb + (size_t)N * 128);     // N*8
  float* stgt = ssrc + (size_t)N * 8;               // N*8
  int* counts = (int*)(stgt + (size_t)N * 8);       // N
  int* offs = counts + N;                           // N+1
  int* nxt = offs + N + 1;                          // N
  int* bsums = nxt + N;                             // 64
  int* esrc = bsums + 64;                           // E

  const int nb = (N + 1023) / 1024;
  const int zb = (N + 255) / 256;

  k_prep<<<CVB + 16 + zb, 256, 0, stream>>>(x, Wp, Ws, xb, Bpk, counts, N * 128, N);
  k_count<<<(E + 255) / 256, 256, 0, stream>>>(ei + E, counts, E);
  k_scan1<<<nb, 1024, 0, stream>>>(counts, offs, bsums, N);
  k_scan3<<<(N + 255) / 256, 256, 0, stream>>>(offs, bsums, nxt, N, E, nb);
  k_scatter<<<(E + 255) / 256, 256, 0, stream>>>(ei, nxt, esrc, E);
  k_gemm<<<PADN / 64, 256, 0, stream>>>(xb, Bpk, pb, sb, ssrc, stgt, a_src, a_tgt, N);
  k_agg<<<(N + 3) / 4, 256, 0, stream>>>(pb, sb, ssrc, stgt, bias, offs, esrc, out, N);
}

// Round 5
// 216.348 us; speedup vs baseline: 1.5651x; 1.1956x over previous
//
#include <hip/hip_runtime.h>
#include <hip/hip_bf16.h>
#include <math.h>

// N=50000, E=800000, IN_DIM=128, HEADS=8, F_OUT=16, HF=128.
#define PADN 50048
#define CVB (PADN / 8)  // blocks for the cvt part of k_prep

typedef __attribute__((ext_vector_type(8))) short short8;
typedef __attribute__((ext_vector_type(4))) float f32x4;

__device__ __forceinline__ unsigned short f2b(float f) {
  __hip_bfloat16 h = __float2bfloat16(f);
  return *(unsigned short*)&h;
}

// ---------------------------------------------------------------------------
// K_prep: fused (a) x fp32->bf16 padded, (b) W-pack into MFMA B-frag order,
// (c) zero counts.  Branch is block-uniform.
// ---------------------------------------------------------------------------
__global__ __launch_bounds__(256) void k_prep(const float* __restrict__ x,
                                              const float* __restrict__ Wp,
                                              const float* __restrict__ Ws,
                                              unsigned short* __restrict__ xb,
                                              unsigned short* __restrict__ Bpk,
                                              int* __restrict__ counts,
                                              int nelem, int N) {
  const int b = blockIdx.x;
  if (b < CVB) {
    int idx = b * 256 + threadIdx.x;  // one float4 per thread
    float4 v = make_float4(0.f, 0.f, 0.f, 0.f);
    if (idx * 4 < nelem) v = ((const float4*)x)[idx];
    ushort4 o;
    o.x = f2b(v.x); o.y = f2b(v.y); o.z = f2b(v.z); o.w = f2b(v.w);
    ((ushort4*)xb)[idx] = o;
  } else if (b < CVB + 16) {
    // Bpk[((tile*4+ks)*64+lane)*8 + j] = W[col][k], col=tile*16+(lane&15),
    // k = ks*32 + (lane>>4)*8 + j; cols 128..255 come from W_skip.
    int idx = (b - CVB) * 256 + threadIdx.x;  // 0..4095
    int tile = idx >> 8;
    int ks = (idx >> 6) & 3;
    int lane = idx & 63;
    int col = tile * 16 + (lane & 15);
    int kbase = ks * 32 + (lane >> 4) * 8;
    const float* src = (col < 128) ? (Wp + (size_t)col * 128 + kbase)
                                   : (Ws + (size_t)(col - 128) * 128 + kbase);
    unsigned short o[8];
#pragma unroll
    for (int j = 0; j < 8; ++j) o[j] = f2b(src[j]);
    *(short8*)(Bpk + (size_t)idx * 8) = *(short8*)o;
  } else {
    int i = (b - CVB - 16) * 256 + threadIdx.x;
    if (i < N) counts[i] = 0;
  }
}

// ---------------------------------------------------------------------------
// K_gemm: [PADN,128]bf16 @ [128,256] -> pb (cols 0-127), sb (cols 128-255),
// B staged in LDS once per block; per-node scores fused in the epilogue.
// ---------------------------------------------------------------------------
__global__ __launch_bounds__(256) void k_gemm(const unsigned short* __restrict__ xb,
                                              const unsigned short* __restrict__ Bpk,
                                              unsigned short* __restrict__ pb,
                                              unsigned short* __restrict__ sb,
                                              float* __restrict__ ssrc,
                                              float* __restrict__ stgt,
                                              const float* __restrict__ a_src,
                                              const float* __restrict__ a_tgt, int N) {
  __shared__ unsigned short Bl[16 * 4 * 64 * 8];  // 64 KB
  {
    const uint4* bg = (const uint4*)Bpk;
    uint4* bl = (uint4*)Bl;
#pragma unroll
    for (int i = 0; i < 16; ++i) bl[threadIdx.x + i * 256] = bg[threadIdx.x + i * 256];
  }
  __syncthreads();

  const int wave = threadIdx.x >> 6, lane = threadIdx.x & 63;
  const int m = lane & 15, q = lane >> 4;
  const int r0 = blockIdx.x * 64 + wave * 16;

  short8 a[4];
#pragma unroll
  for (int ks = 0; ks < 4; ++ks)
    a[ks] = *(const short8*)(xb + (size_t)(r0 + m) * 128 + ks * 32 + q * 8);

  for (int ct = 0; ct < 16; ++ct) {
    f32x4 acc = {0.f, 0.f, 0.f, 0.f};
#pragma unroll
    for (int ks = 0; ks < 4; ++ks) {
      short8 bfr = *(const short8*)(Bl + (size_t)((ct * 4 + ks) * 64 + lane) * 8);
      acc = __builtin_amdgcn_mfma_f32_16x16x32_bf16(a[ks], bfr, acc, 0, 0, 0);
    }
    unsigned short* dst = (ct < 8) ? pb : sb;
    const int cc = (ct & 7) * 16 + m;
#pragma unroll
    for (int r = 0; r < 4; ++r) {
      int row = r0 + q * 4 + r;
      if (row < N) dst[(size_t)row * 128 + cc] = f2b(acc[r]);
    }
    if (ct < 8) {  // head ct: s_src/s_tgt dot over the 16 cols (lane dim m)
      const float as = a_src[ct * 16 + m];
      const float at = a_tgt[ct * 16 + m];
#pragma unroll
      for (int r = 0; r < 4; ++r) {
        float vs = acc[r] * as;
        float vt = acc[r] * at;
#pragma unroll
        for (int off = 8; off >= 1; off >>= 1) {
          vs += __shfl_xor(vs, off);
          vt += __shfl_xor(vt, off);
        }
        int row = r0 + q * 4 + r;
        if (m == 0 && row < N) {
          ssrc[row * 8 + ct] = vs;
          stgt[row * 8 + ct] = vt;
        }
      }
    }
  }
}

// ---------------------------------------------------------------------------
// CSR build — single atomic pass. atomicAdd's return IS the within-segment
// rank. Stride T == total thread count so the (tid,p)->edge map is INJECTIVE
// (the round-4 crash was T=E/4 < thread count -> 192 edges double-counted ->
// unwritten poisoned esrc slots -> wild gathers).
// ---------------------------------------------------------------------------
__global__ __launch_bounds__(256) void k_count_rank(const int* __restrict__ tgt,
                                                    int* __restrict__ counts,
                                                    int* __restrict__ rank, int E) {
  const int tid = blockIdx.x * 256 + threadIdx.x;
  const int T = gridDim.x * 256;  // injective: e = tid + p*T, tid < T
  int e0 = tid, e1 = tid + T, e2 = tid + 2 * T, e3 = tid + 3 * T;
  int t0 = (e0 < E) ? tgt[e0] : 0;
  int t1 = (e1 < E) ? tgt[e1] : 0;
  int t2 = (e2 < E) ? tgt[e2] : 0;
  int t3 = (e3 < E) ? tgt[e3] : 0;
  int r0 = 0, r1 = 0, r2 = 0, r3 = 0;
  if (e0 < E) r0 = atomicAdd(&counts[t0], 1);
  if (e1 < E) r1 = atomicAdd(&counts[t1], 1);
  if (e2 < E) r2 = atomicAdd(&counts[t2], 1);
  if (e3 < E) r3 = atomicAdd(&counts[t3], 1);
  if (e0 < E) rank[e0] = r0;
  if (e1 < E) rank[e1] = r1;
  if (e2 < E) rank[e2] = r2;
  if (e3 < E) rank[e3] = r3;
}

__global__ __launch_bounds__(1024) void k_scan1(const int* __restrict__ counts,
                                                int* __restrict__ offs,
                                                int* __restrict__ bsums, int N) {
  __shared__ int sm[1024];
  int t = threadIdx.x;
  int i = blockIdx.x * 1024 + t;
  int v = (i < N) ? counts[i] : 0;
  sm[t] = v;
  __syncthreads();
  for (int off = 1; off < 1024; off <<= 1) {
    int u = (t >= off) ? sm[t - off] : 0;
    __syncthreads();
    sm[t] += u;
    __syncthreads();
  }
  if (i < N) offs[i] = sm[t] - v;          // block-local exclusive
  if (t == 1023) bsums[blockIdx.x] = sm[t];  // block total
}

// scan of block totals folded in: every wave scans bsums (nb<=64) in-register.
__global__ void k_scan3(int* __restrict__ offs, const int* __restrict__ bsums,
                        int N, int E, int nb) {
  int i = blockIdx.x * blockDim.x + threadIdx.x;
  int lane = threadIdx.x & 63;
  int incl = (lane < nb) ? bsums[lane] : 0;
#pragma unroll
  for (int off = 1; off < 64; off <<= 1) {
    int u = __shfl_up(incl, off);
    if (lane >= off) incl += u;
  }
  int g = i >> 10;  // wave-uniform (64 | 1024)
  int pre = __shfl(incl, (g > 0) ? (g - 1) : 0);
  if (g == 0) pre = 0;
  if (i < N) offs[i] += pre;
  if (i == 0) offs[N] = E;
}

// Placement: no atomics, fire-and-forget scattered stores; offs gathers are
// L2-resident. Same injective strided mapping as k_count_rank.
__global__ __launch_bounds__(256) void k_place(const int* __restrict__ ei,
                                               const int* __restrict__ offs,
                                               const int* __restrict__ rank,
                                               int* __restrict__ esrc, int E) {
  const int tid = blockIdx.x * 256 + threadIdx.x;
  const int T = gridDim.x * 256;
#pragma unroll
  for (int p = 0; p < 4; ++p) {
    int e = tid + p * T;
    if (e < E) esrc[offs[ei[E + e]] + rank[e]] = ei[e];
  }
}

// ---------------------------------------------------------------------------
// K_agg: one wave per target node; shift-free online softmax; depth-8
// software-pipelined bf16 proj gathers; fused skip+bias+ELU.
// Lane l: cols 2l,2l+1; head h=l>>3.
// ---------------------------------------------------------------------------
__global__ __launch_bounds__(256) void k_agg(const unsigned short* __restrict__ pb,
                                             const unsigned short* __restrict__ sb,
                                             const float* __restrict__ ssrc,
                                             const float* __restrict__ stgt,
                                             const float* __restrict__ bias,
                                             const int* __restrict__ offs,
                                             const int* __restrict__ esrc,
                                             float* __restrict__ out, int N) {
  int wid = (int)((blockIdx.x * (size_t)blockDim.x + threadIdx.x) >> 6);
  int lane = threadIdx.x & 63;
  if (wid >= N) return;
  const int n = wid;
  const int c = lane * 2;
  const int h = lane >> 3;

  const float st = stgt[n * 8 + h];
  const int begin = offs[n];
  const int end = offs[n + 1];

  float ds0 = 0.f, ds1 = 0.f, ds2 = 0.f, ds3 = 0.f;
  float x00 = 0.f, x01 = 0.f, x10 = 0.f, x11 = 0.f;
  float x20 = 0.f, x21 = 0.f, x30 = 0.f, x31 = 0.f;

  const unsigned short* pbc = pb + c;

#define FILLQ(p, jj)                                             \
  {                                                              \
    int s_ = __shfl(srcv, (jj));                                 \
    pv##p = *(const unsigned int*)(pbc + (size_t)s_ * 128);      \
    sc##p = ssrc[s_ * 8 + h];                                    \
  }
#define EDGEQ(p, dsx, a0x, a1x)                                  \
  {                                                              \
    float e_ = sc##p + st;                                       \
    e_ = (e_ > 0.f) ? e_ : 0.2f * e_;                            \
    float w_ = __expf(e_);                                       \
    dsx += w_;                                                   \
    a0x = fmaf(w_, __uint_as_float(pv##p << 16), a0x);           \
    a1x = fmaf(w_, __uint_as_float(pv##p & 0xffff0000u), a1x);   \
  }

  for (int base = begin; base < end; base += 64) {
    const int cnt = min(64, end - base);
    const int cm = cnt - 1;
    int srcv = esrc[base + min(lane, cm)];
    unsigned int pv0, pv1, pv2, pv3, pv4, pv5, pv6, pv7;
    float sc0, sc1, sc2, sc3, sc4, sc5, sc6, sc7;

    FILLQ(0, 0)
    FILLQ(1, min(1, cm))
    FILLQ(2, min(2, cm))
    FILLQ(3, min(3, cm))
    FILLQ(4, min(4, cm))
    FILLQ(5, min(5, cm))
    FILLQ(6, min(6, cm))
    FILLQ(7, min(7, cm))

    int j = 0;
    for (; j + 8 <= cnt; j += 8) {
      EDGEQ(0, ds0, x00, x01)
      EDGEQ(1, ds1, x10, x11)
      EDGEQ(2, ds2, x20, x21)
      EDGEQ(3, ds3, x30, x31)
      FILLQ(0, min(j + 8, cm))
      FILLQ(1, min(j + 9, cm))
      FILLQ(2, min(j + 10, cm))
      FILLQ(3, min(j + 11, cm))
      EDGEQ(4, ds0, x00, x01)
      EDGEQ(5, ds1, x10, x11)
      EDGEQ(6, ds2, x20, x21)
      EDGEQ(7, ds3, x30, x31)
      FILLQ(4, min(j + 12, cm))
      FILLQ(5, min(j + 13, cm))
      FILLQ(6, min(j + 14, cm))
      FILLQ(7, min(j + 15, cm))
    }
    const int rem = cnt - j;  // 0..7
    if (rem > 0) EDGEQ(0, ds0, x00, x01)
    if (rem > 1) EDGEQ(1, ds1, x10, x11)
    if (rem > 2) EDGEQ(2, ds2, x20, x21)
    if (rem > 3) EDGEQ(3, ds3, x30, x31)
    if (rem > 4) EDGEQ(4, ds0, x00, x01)
    if (rem > 5) EDGEQ(5, ds1, x10, x11)
    if (rem > 6) EDGEQ(6, ds2, x20, x21)
  }
#undef FILLQ
#undef EDGEQ

  const float dsum = (ds0 + ds1) + (ds2 + ds3);
  const float acc0 = (x00 + x10) + (x20 + x30);
  const float acc1 = (x01 + x11) + (x21 + x31);
  const float inv = 1.0f / (dsum + 1e-16f);
  size_t row = (size_t)n * 128;
  unsigned int su = *(const unsigned int*)(sb + row + c);
  float sk0 = __uint_as_float(su << 16);
  float sk1 = __uint_as_float(su & 0xffff0000u);
  float r0 = fmaf(acc0, inv, sk0) + bias[c];
  float r1 = fmaf(acc1, inv, sk1) + bias[c + 1];
  r0 = (r0 > 0.f) ? r0 : (expf(r0) - 1.0f);  // ELU
  r1 = (r1 > 0.f) ? r1 : (expf(r1) - 1.0f);
  *(float2*)(out + row + c) = make_float2(r0, r1);
}

// ---------------------------------------------------------------------------
extern "C" void kernel_launch(void* const* d_in, const int* in_sizes, int n_in,
                              void* d_out, int out_size, void* d_ws, size_t ws_size,
                              hipStream_t stream) {
  const float* x = (const float*)d_in[0];
  const int* ei = (const int*)d_in[1];
  const float* Wp = (const float*)d_in[2];
  const float* a_src = (const float*)d_in[3];
  const float* a_tgt = (const float*)d_in[4];
  const float* Ws = (const float*)d_in[5];
  const float* bias = (const float*)d_in[6];
  float* out = (float*)d_out;

  const int N = in_sizes[0] / 128;  // 50000
  const int E = in_sizes[1] / 2;    // 800000

  // workspace layout (~48.5 MB)
  unsigned short* xb = (unsigned short*)d_ws;       // PADN*128 bf16
  unsigned short* Bpk = xb + (size_t)PADN * 128;    // 32768 bf16
  unsigned short* pb = Bpk + 32768;                 // N*128 bf16
  unsigned short* sb = pb + (size_t)N * 128;        // N*128 bf16
  float* ssrc = (float*)(sb + (size_t)N * 128);     // N*8
  float* stgt = ssrc + (size_t)N * 8;               // N*8
  int* counts = (int*)(stgt + (size_t)N * 8);       // N
  int* offs = counts + N;                           // N+1
  int* bsums = offs + N + 1;                        // 64
  int* rank = bsums + 64;                           // E
  int* esrc = rank + E;                             // E

  const int nb = (N + 1023) / 1024;
  const int zb = (N + 255) / 256;
  const int eb = (E + 4 * 256 - 1) / (4 * 256);  // 4 edges/thread

  k_prep<<<CVB + 16 + zb, 256, 0, stream>>>(x, Wp, Ws, xb, Bpk, counts, N * 128, N);
  k_count_rank<<<eb, 256, 0, stream>>>(ei + E, counts, rank, E);
  k_scan1<<<nb, 1024, 0, stream>>>(counts, offs, bsums, N);
  k_scan3<<<(N + 255) / 256, 256, 0, stream>>>(offs, bsums, N, E, nb);
  k_place<<<eb, 256, 0, stream>>>(ei, offs, rank, esrc, E);
  k_gemm<<<PADN / 64, 256, 0, stream>>>(xb, Bpk, pb, sb, ssrc, stgt, a_src, a_tgt, N);
  k_agg<<<(N + 3) / 4, 256, 0, stream>>>(pb, sb, ssrc, stgt, bias, offs, esrc, out, N);
}